// Round 1
// baseline (1376.403 us; speedup 1.0000x reference)
//
#include <hip/hip_runtime.h>
#include <stdint.h>

#define NT      360000
#define NTRACE  96
#define MEDK    6000
#define MSTRIDE 3000
#define NW      121      // number of MAD windows per trace
#define HALFW   50       // maxpool half-window (101 total)
#define TOPK    100
#define DETCAP  128      // max detections stored per trace (expected: 0)
#define RATIO_F 10.0f
#define DCHUNKS 12       // detect kernel: chunks per trace (30000 samples each)

// ---- float <-> sortable key (total order, -0.0 < +0.0, matches XLA top_k) ----
__device__ __forceinline__ uint32_t f2key(float f) {
    uint32_t u = __float_as_uint(f);
    return (u & 0x80000000u) ? ~u : (u | 0x80000000u);
}
__device__ __forceinline__ float key2f(uint32_t k) {
    uint32_t u = (k & 0x80000000u) ? (k & 0x7fffffffu) : ~k;
    return __uint_as_float(u);
}

// Exact 3000th-smallest (0-indexed rank 2999 == lower median of 6000) via
// 4x8-bit MSB radix select. ls[] stays unchanged; for the MAD phase the key is
// computed on the fly as |ls[i] - sub|.
__device__ float radix_select6000(const float* ls, float sub, bool useabs,
                                  uint32_t* hist, uint32_t* s_bin, uint32_t* s_rank)
{
    const int tid = threadIdx.x;
    const int wv  = tid >> 6;            // per-wave histogram copy (contention)
    uint32_t prefix = 0, pmask = 0, rank = 3000;   // 1-indexed k-th smallest
    for (int pass = 0; pass < 4; ++pass) {
        const int shift = 24 - 8 * pass;
        for (int i = tid; i < 1024; i += 256) hist[i] = 0;
        __syncthreads();
        for (int i = tid; i < MEDK; i += 256) {
            float v = ls[i];
            if (useabs) v = fabsf(v - sub);
            uint32_t k = f2key(v);
            if ((k & pmask) == prefix)
                atomicAdd(&hist[wv * 256 + ((k >> shift) & 0xFFu)], 1u);
        }
        __syncthreads();
        if (tid == 0) {
            uint32_t acc = 0;
            for (int b = 0; b < 256; ++b) {
                uint32_t c = hist[b] + hist[256 + b] + hist[512 + b] + hist[768 + b];
                if (acc + c >= rank) { *s_bin = (uint32_t)b; *s_rank = rank - acc; break; }
                acc += c;
            }
        }
        __syncthreads();
        prefix |= (*s_bin) << shift;
        pmask  |= 0xFFu << shift;
        rank    = *s_rank;
        __syncthreads();
    }
    return key2f(prefix);
}

__global__ __launch_bounds__(256) void mad_kernel(const float* __restrict__ x,
                                                  float* __restrict__ mad)
{
    __shared__ float    ls[MEDK];        // 24000 B
    __shared__ uint32_t hist[1024];      // 4096 B
    __shared__ uint32_t s_bin, s_rank;
    const int tr = blockIdx.x / NW;
    const int w  = blockIdx.x % NW;
    const float* xt = x + (size_t)tr * NT;
    const int t0 = w * MSTRIDE;
    for (int i = threadIdx.x; i < MEDK; i += 256) {
        int g = t0 + i;
        int src = (g < NT) ? g : (2 * NT - 2 - g);   // numpy 'reflect' (no edge)
        ls[i] = xt[src];
    }
    __syncthreads();
    float med  = radix_select6000(ls, 0.0f, false, hist, &s_bin, &s_rank);
    __syncthreads();
    float madv = radix_select6000(ls, med,  true,  hist, &s_bin, &s_rank);
    if (threadIdx.x == 0) mad[tr * NW + w] = madv;
}

__global__ __launch_bounds__(256) void detect_kernel(const float* __restrict__ x,
                                                     const float* __restrict__ mad,
                                                     uint32_t* __restrict__ counters,
                                                     uint64_t* __restrict__ det)
{
    __shared__ float smad[NW];
    const int tr = blockIdx.x / DCHUNKS;
    const int ch = blockIdx.x % DCHUNKS;
    const float* xt = x + (size_t)tr * NT;
    for (int i = threadIdx.x; i < NW; i += 256) smad[i] = mad[tr * NW + i];
    __syncthreads();
    const int tbeg = ch * (NT / DCHUNKS);
    const int tend = tbeg + (NT / DCHUNKS);
    for (int t = tbeg + threadIdx.x; t < tend; t += 256) {
        float v = xt[t];
        // bilinear interp of mad along time (align_corners=False, clamped)
        float pos = ((float)t + 0.5f) / (float)MSTRIDE - 0.5f;
        pos = fmaxf(pos, 0.0f);
        int   x0 = min((int)floorf(pos), NW - 1);
        int   x1 = min(x0 + 1, NW - 1);
        float wg = pos - (float)x0;
        float m  = smad[x0] * (1.0f - wg) + smad[x1] * wg;
        if (v > RATIO_F * m) {                       // almost never true
            bool ismax = true;
            int lo = max(t - HALFW, 0), hi = min(t + HALFW, NT - 1);
            for (int j = lo; j <= hi && ismax; ++j) ismax = (xt[j] <= v);
            if (ismax) {
                uint32_t slot = atomicAdd(&counters[tr], 1u);
                if (slot < DETCAP)
                    det[(size_t)tr * DETCAP + slot] =
                        ((uint64_t)f2key(v) << 32) | (uint32_t)(~(uint32_t)t);
            }
        }
    }
}

__global__ __launch_bounds__(64) void finalize_kernel(const float* __restrict__ x,
                                                      const uint32_t* __restrict__ counters,
                                                      const uint64_t* __restrict__ det,
                                                      float* __restrict__ out)
{
    __shared__ uint64_t sdet[DETCAP];
    __shared__ int sposs[TOPK];
    __shared__ int snegs[TOPK];
    __shared__ int s_np, s_nn;
    const int tr   = blockIdx.x;
    const int lane = threadIdx.x;
    const int D = (int)min(counters[tr], (uint32_t)DETCAP);
    for (int i = lane; i < D; i += 64) sdet[i] = det[(size_t)tr * DETCAP + i];
    if (lane == 0) { s_np = 0; s_nn = 0; }
    __syncthreads();

    const float* xt = x + (size_t)tr * NT;
    // collect first TOPK non-negative-sign (excluding detections) and first
    // TOPK negative-sign indices, in ascending index order
    for (int base = 0; base < NT; base += 64) {
        int np0 = s_np, nn0 = s_nn;
        if (np0 >= TOPK && nn0 >= TOPK) break;
        int  t     = base + lane;
        bool valid = (t < NT);
        uint32_t bits = valid ? __float_as_uint(xt[t]) : 0u;
        bool nonneg = valid && !(bits >> 31);
        bool neg    = valid &&  (bits >> 31);
        if (nonneg && D > 0) {
            for (int i = 0; i < D; ++i) {
                int dt = (int)(~(uint32_t)(sdet[i] & 0xFFFFFFFFull));
                if (dt == t) { nonneg = false; break; }
            }
        }
        unsigned long long bp = __ballot(nonneg);
        unsigned long long bn = __ballot(neg);
        unsigned long long below = (1ull << lane) - 1ull;
        int pidx = np0 + __popcll(bp & below);
        int nidx = nn0 + __popcll(bn & below);
        if (nonneg && pidx < TOPK) sposs[pidx] = t;
        if (neg    && nidx < TOPK) snegs[nidx] = t;
        __syncthreads();
        if (lane == 0) { s_np = np0 + __popcll(bp); s_nn = nn0 + __popcll(bn); }
        __syncthreads();
    }
    __syncthreads();

    if (lane == 0) {  // sort detections descending by total-order key (D tiny)
        for (int i = 1; i < D; ++i) {
            uint64_t k = sdet[i]; int j = i - 1;
            while (j >= 0 && sdet[j] < k) { sdet[j + 1] = sdet[j]; --j; }
            sdet[j + 1] = k;
        }
    }
    __syncthreads();

    const int nd   = min(D, TOPK);
    const int npos = min(s_np, TOPK);
    float* oscore = out + (size_t)tr * TOPK;
    float* oidx   = out + (size_t)NTRACE * TOPK + (size_t)tr * TOPK;
    for (int j = lane; j < TOPK; j += 64) {
        float sc; int idx;
        if (j < nd) {
            uint64_t k = sdet[j];
            sc  = key2f((uint32_t)(k >> 32));
            idx = (int)(~(uint32_t)(k & 0xFFFFFFFFull));
        } else if (j - nd < npos) {
            sc = 0.0f;  idx = sposs[j - nd];
        } else {
            int jj = j - nd - npos;
            sc = -0.0f; idx = (jj < TOPK) ? snegs[jj] : 0;
        }
        oscore[j] = sc;
        oidx[j]   = (float)idx;   // tuple output buffer is read back as f32
    }
}

extern "C" void kernel_launch(void* const* d_in, const int* in_sizes, int n_in,
                              void* d_out, int out_size, void* d_ws, size_t ws_size,
                              hipStream_t stream)
{
    const float* x = (const float*)d_in[0];
    float* out = (float*)d_out;
    char* ws = (char*)d_ws;
    float*    mad      = (float*)ws;                       // 96*121*4 = 46464 B
    uint32_t* counters = (uint32_t*)(ws + 46464);          // 384 B
    uint64_t* det      = (uint64_t*)(ws + 46464 + 384);    // 96*128*8 B (8-aligned)

    hipMemsetAsync(counters, 0, NTRACE * sizeof(uint32_t), stream);
    hipLaunchKernelGGL(mad_kernel,    dim3(NTRACE * NW),      dim3(256), 0, stream, x, mad);
    hipLaunchKernelGGL(detect_kernel, dim3(NTRACE * DCHUNKS), dim3(256), 0, stream, x, mad, counters, det);
    hipLaunchKernelGGL(finalize_kernel, dim3(NTRACE),         dim3(64),  0, stream, x, counters, det, out);
}

// Round 2
// 607.346 us; speedup vs baseline: 2.2663x; 2.2663x over previous
//
#include <hip/hip_runtime.h>
#include <stdint.h>

#define NT      360000
#define NTRACE  96
#define MEDK    6000
#define MSTRIDE 3000
#define NW      121      // number of MAD windows per trace
#define HALFW   50       // maxpool half-window (101 total)
#define TOPK    100
#define DETCAP  128      // max detections stored per trace (expected: 0)
#define RATIO_F 10.0f
#define DCHUNKS 12       // detect kernel: chunks per trace (30000 samples each)

// ---- float <-> sortable key (total order, -0.0 < +0.0, matches XLA top_k) ----
__device__ __forceinline__ uint32_t f2key(float f) {
    uint32_t u = __float_as_uint(f);
    return (u & 0x80000000u) ? ~u : (u | 0x80000000u);
}
__device__ __forceinline__ float key2f(uint32_t k) {
    uint32_t u = (k & 0x80000000u) ? (k & 0x7fffffffu) : ~k;
    return __uint_as_float(u);
}

struct SelShared {
    uint32_t hist[1024];     // 4 per-wave copies of 256 bins
    uint32_t scan_a[256];
    uint32_t scan_b[256];
    uint32_t s_bin, s_rank;
};

// Exact k-th smallest (rank 3000 1-indexed == lower median of 6000) via
// 4x8-bit MSB radix select. Bin selection is a parallel 256-wide prefix scan
// (the previous serial tid==0 scan was ~245K cycles/block of LDS latency).
__device__ float radix_select6000(const float* ls, float sub, bool useabs,
                                  SelShared* sh)
{
    const int tid = threadIdx.x;
    const int wv  = tid >> 6;            // per-wave histogram copy
    uint32_t prefix = 0, pmask = 0, rank = 3000;   // 1-indexed k-th smallest
    for (int pass = 0; pass < 4; ++pass) {
        const int shift = 24 - 8 * pass;
        for (int i = tid; i < 1024; i += 256) sh->hist[i] = 0;
        __syncthreads();
        for (int i = tid; i < MEDK; i += 256) {
            float v = ls[i];
            if (useabs) v = fabsf(v - sub);
            uint32_t k = f2key(v);
            if ((k & pmask) == prefix)
                atomicAdd(&sh->hist[wv * 256 + ((k >> shift) & 0xFFu)], 1u);
        }
        __syncthreads();
        uint32_t c = sh->hist[tid] + sh->hist[256 + tid] +
                     sh->hist[512 + tid] + sh->hist[768 + tid];
        sh->scan_a[tid] = c;
        __syncthreads();
        // Hillis-Steele inclusive scan over 256 bins (8 steps, ping-pong)
        uint32_t* src = sh->scan_a;
        uint32_t* dst = sh->scan_b;
        for (int off = 1; off < 256; off <<= 1) {
            uint32_t v = src[tid];
            if (tid >= off) v += src[tid - off];
            dst[tid] = v;
            __syncthreads();
            uint32_t* t = src; src = dst; dst = t;
        }
        uint32_t incl = src[tid];       // after 8 swaps src == scan_a
        uint32_t excl = incl - c;
        if (incl >= rank && excl < rank) {   // exactly one thread true
            sh->s_bin  = (uint32_t)tid;
            sh->s_rank = rank - excl;
        }
        __syncthreads();
        prefix |= sh->s_bin << shift;
        pmask  |= 0xFFu << shift;
        rank    = sh->s_rank;
        __syncthreads();
    }
    return key2f(prefix);
}

__global__ __launch_bounds__(256) void mad_kernel(const float* __restrict__ x,
                                                  float* __restrict__ mad)
{
    __shared__ float    ls[MEDK];        // 24000 B
    __shared__ SelShared sh;             // ~6.2 KB
    const int tr = blockIdx.x / NW;
    const int w  = blockIdx.x % NW;
    const float* xt = x + (size_t)tr * NT;
    const int t0 = w * MSTRIDE;
    if (t0 + MEDK <= NT) {
        // interior window: t0*4 bytes is 16B-aligned (3000*4 % 16 == 0)
        const float4* src4 = (const float4*)(xt + t0);
        float4* dst4 = (float4*)ls;
        for (int i = threadIdx.x; i < MEDK / 4; i += 256) dst4[i] = src4[i];
    } else {
        for (int i = threadIdx.x; i < MEDK; i += 256) {
            int g = t0 + i;
            int src = (g < NT) ? g : (2 * NT - 2 - g);   // numpy 'reflect'
            ls[i] = xt[src];
        }
    }
    __syncthreads();
    float med  = radix_select6000(ls, 0.0f, false, &sh);
    __syncthreads();
    float madv = radix_select6000(ls, med,  true,  &sh);
    if (threadIdx.x == 0) mad[tr * NW + w] = madv;
}

__global__ __launch_bounds__(256) void detect_kernel(const float* __restrict__ x,
                                                     const float* __restrict__ mad,
                                                     uint32_t* __restrict__ counters,
                                                     uint64_t* __restrict__ det)
{
    __shared__ float smad[NW];
    const int tr = blockIdx.x / DCHUNKS;
    const int ch = blockIdx.x % DCHUNKS;
    const float* xt = x + (size_t)tr * NT;
    for (int i = threadIdx.x; i < NW; i += 256) smad[i] = mad[tr * NW + i];
    __syncthreads();
    const int tbeg = ch * (NT / DCHUNKS);
    const int tend = tbeg + (NT / DCHUNKS);
    for (int t = tbeg + threadIdx.x * 4; t < tend; t += 256 * 4) {
        float4 v4 = *(const float4*)(xt + t);    // tbeg,t multiples of 4 -> aligned
        float vv[4] = {v4.x, v4.y, v4.z, v4.w};
        #pragma unroll
        for (int k = 0; k < 4; ++k) {
            int   tt = t + k;
            float v  = vv[k];
            // bilinear interp of mad along time (align_corners=False, clamped)
            float pos = ((float)tt + 0.5f) / (float)MSTRIDE - 0.5f;
            pos = fmaxf(pos, 0.0f);
            int   x0 = min((int)floorf(pos), NW - 1);
            int   x1 = min(x0 + 1, NW - 1);
            float wg = pos - (float)x0;
            float m  = smad[x0] * (1.0f - wg) + smad[x1] * wg;
            if (v > RATIO_F * m) {                       // almost never true
                bool ismax = true;
                int lo = max(tt - HALFW, 0), hi = min(tt + HALFW, NT - 1);
                for (int j = lo; j <= hi && ismax; ++j) ismax = (xt[j] <= v);
                if (ismax) {
                    uint32_t slot = atomicAdd(&counters[tr], 1u);
                    if (slot < DETCAP)
                        det[(size_t)tr * DETCAP + slot] =
                            ((uint64_t)f2key(v) << 32) | (uint32_t)(~(uint32_t)tt);
                }
            }
        }
    }
}

__global__ __launch_bounds__(64) void finalize_kernel(const float* __restrict__ x,
                                                      const uint32_t* __restrict__ counters,
                                                      const uint64_t* __restrict__ det,
                                                      float* __restrict__ out)
{
    __shared__ uint64_t sdet[DETCAP];
    __shared__ int sposs[TOPK];
    __shared__ int snegs[TOPK];
    __shared__ int s_np, s_nn;
    const int tr   = blockIdx.x;
    const int lane = threadIdx.x;
    const int D = (int)min(counters[tr], (uint32_t)DETCAP);
    for (int i = lane; i < D; i += 64) sdet[i] = det[(size_t)tr * DETCAP + i];
    if (lane == 0) { s_np = 0; s_nn = 0; }
    __syncthreads();

    const float* xt = x + (size_t)tr * NT;
    // first TOPK non-negative-sign (excluding detections) and first TOPK
    // negative-sign indices, ascending index order (XLA top_k tie semantics:
    // masked = x*0 keeps the sign; +0.0 sorts above -0.0, ties by index)
    for (int base = 0; base < NT; base += 64) {
        int np0 = s_np, nn0 = s_nn;
        if (np0 >= TOPK && nn0 >= TOPK) break;
        int  t     = base + lane;
        bool valid = (t < NT);
        uint32_t bits = valid ? __float_as_uint(xt[t]) : 0u;
        bool nonneg = valid && !(bits >> 31);
        bool neg    = valid &&  (bits >> 31);
        if (nonneg && D > 0) {
            for (int i = 0; i < D; ++i) {
                int dt = (int)(~(uint32_t)(sdet[i] & 0xFFFFFFFFull));
                if (dt == t) { nonneg = false; break; }
            }
        }
        unsigned long long bp = __ballot(nonneg);
        unsigned long long bn = __ballot(neg);
        unsigned long long below = (1ull << lane) - 1ull;
        int pidx = np0 + __popcll(bp & below);
        int nidx = nn0 + __popcll(bn & below);
        if (nonneg && pidx < TOPK) sposs[pidx] = t;
        if (neg    && nidx < TOPK) snegs[nidx] = t;
        __syncthreads();
        if (lane == 0) { s_np = np0 + __popcll(bp); s_nn = nn0 + __popcll(bn); }
        __syncthreads();
    }
    __syncthreads();

    if (lane == 0) {  // sort detections descending by total-order key (D tiny)
        for (int i = 1; i < D; ++i) {
            uint64_t k = sdet[i]; int j = i - 1;
            while (j >= 0 && sdet[j] < k) { sdet[j + 1] = sdet[j]; --j; }
            sdet[j + 1] = k;
        }
    }
    __syncthreads();

    const int nd   = min(D, TOPK);
    const int npos = min(s_np, TOPK);
    float* oscore = out + (size_t)tr * TOPK;
    float* oidx   = out + (size_t)NTRACE * TOPK + (size_t)tr * TOPK;
    for (int j = lane; j < TOPK; j += 64) {
        float sc; int idx;
        if (j < nd) {
            uint64_t k = sdet[j];
            sc  = key2f((uint32_t)(k >> 32));
            idx = (int)(~(uint32_t)(k & 0xFFFFFFFFull));
        } else if (j - nd < npos) {
            sc = 0.0f;  idx = sposs[j - nd];
        } else {
            int jj = j - nd - npos;
            sc = -0.0f; idx = (jj < TOPK) ? snegs[jj] : 0;
        }
        oscore[j] = sc;
        oidx[j]   = (float)idx;   // tuple output buffer is read back as f32
    }
}

extern "C" void kernel_launch(void* const* d_in, const int* in_sizes, int n_in,
                              void* d_out, int out_size, void* d_ws, size_t ws_size,
                              hipStream_t stream)
{
    const float* x = (const float*)d_in[0];
    float* out = (float*)d_out;
    char* ws = (char*)d_ws;
    float*    mad      = (float*)ws;                       // 96*121*4 = 46464 B
    uint32_t* counters = (uint32_t*)(ws + 46464);          // 384 B
    uint64_t* det      = (uint64_t*)(ws + 46464 + 384);    // 96*128*8 B (8-aligned)

    hipMemsetAsync(counters, 0, NTRACE * sizeof(uint32_t), stream);
    hipLaunchKernelGGL(mad_kernel,    dim3(NTRACE * NW),      dim3(256), 0, stream, x, mad);
    hipLaunchKernelGGL(detect_kernel, dim3(NTRACE * DCHUNKS), dim3(256), 0, stream, x, mad, counters, det);
    hipLaunchKernelGGL(finalize_kernel, dim3(NTRACE),         dim3(64),  0, stream, x, counters, det, out);
}

// Round 3
// 550.378 us; speedup vs baseline: 2.5008x; 1.1035x over previous
//
#include <hip/hip_runtime.h>
#include <stdint.h>

#define NT      360000
#define NTRACE  96
#define MEDK    6000
#define MSTRIDE 3000
#define NW      121      // number of MAD windows per trace
#define HALFW   50       // maxpool half-window (101 total)
#define TOPK    100
#define DETCAP  128      // max detections stored per trace (expected: 0)
#define RATIO_F 10.0f
#define DCHUNKS 12       // detect kernel: chunks per trace (30000 samples each)
#define CAP     2304     // compaction buffer (MAD bin ~1800+5sigma < 2304)

// ---- float <-> sortable key (total order, -0.0 < +0.0, matches XLA top_k) ----
__device__ __forceinline__ uint32_t f2key(float f) {
    uint32_t u = __float_as_uint(f);
    return u ^ (uint32_t)(((int32_t)u >> 31) | 0x80000000);   // 3 VALU, branchless
}
__device__ __forceinline__ float key2f(uint32_t k) {
    uint32_t u = (k & 0x80000000u) ? (k & 0x7fffffffu) : ~k;
    return __uint_as_float(u);
}

struct SelShared {
    uint32_t hist[1024];     // 4 per-wave copies of 256 bins
    uint32_t cmp[CAP];       // compacted keys of the pass-0 winning bin
    uint32_t segtot[4];
    uint32_t s_bin, s_rank, s_cnt, ccount;
};

// Find bin containing `rank` from 4-copy 256-bin histogram.
// Wave shuffle-scan + 4-segment combine: 2 barriers (was 16 with Hillis-Steele).
__device__ void bin_select(SelShared* sh, uint32_t rank)
{
    const int tid  = threadIdx.x;
    const int lane = tid & 63;
    const int wv   = tid >> 6;
    uint32_t c = sh->hist[tid] + sh->hist[256 + tid] +
                 sh->hist[512 + tid] + sh->hist[768 + tid];
    uint32_t incl = c;
    #pragma unroll
    for (int off = 1; off < 64; off <<= 1) {
        uint32_t v = __shfl_up(incl, off);
        if (lane >= off) incl += v;
    }
    if (lane == 63) sh->segtot[wv] = incl;
    __syncthreads();
    uint32_t segoff = 0;
    for (int j = 0; j < wv; ++j) segoff += sh->segtot[j];
    incl += segoff;
    uint32_t excl = incl - c;
    if (rank > excl && rank <= incl) {   // exactly one thread true
        sh->s_bin = (uint32_t)tid; sh->s_rank = rank - excl; sh->s_cnt = c;
    }
    __syncthreads();
}

// Exact 3000th-smallest (1-indexed == lower median of 6000). Pass 0: 8-bit MSB
// histogram; then COMPACT the winning bin (normally 50..2000 elems for this
// data) and run passes 1-3 over the compacted keys. Fallback to full-array
// filtered passes if the bin overflows CAP (exactness for arbitrary input).
__device__ float select_rank3000(const float* ls, float sub, bool useabs,
                                 SelShared* sh)
{
    const int tid = threadIdx.x;
    const int wv  = tid >> 6;
    uint32_t* myhist = &sh->hist[wv * 256];

    for (int i = tid; i < 1024; i += 256) sh->hist[i] = 0;
    if (tid == 0) sh->ccount = 0;
    __syncthreads();
    for (int i = tid; i < MEDK / 4; i += 256) {
        float4 v4 = ((const float4*)ls)[i];
        float vv[4] = {v4.x, v4.y, v4.z, v4.w};
        #pragma unroll
        for (int e = 0; e < 4; ++e) {
            float v = vv[e];
            if (useabs) v = fabsf(v - sub);
            atomicAdd(&myhist[f2key(v) >> 24], 1u);
        }
    }
    __syncthreads();
    bin_select(sh, 3000u);
    const uint32_t b0 = sh->s_bin, cnt = sh->s_cnt;
    uint32_t rank   = sh->s_rank;
    uint32_t prefix = b0 << 24;
    uint32_t pmask  = 0xFF000000u;
    const bool usec = (cnt <= CAP);

    if (usec) {   // compact winning-bin keys into cmp[]
        for (int i = tid; i < MEDK / 4; i += 256) {
            float4 v4 = ((const float4*)ls)[i];
            float vv[4] = {v4.x, v4.y, v4.z, v4.w};
            #pragma unroll
            for (int e = 0; e < 4; ++e) {
                float v = vv[e];
                if (useabs) v = fabsf(v - sub);
                uint32_t k = f2key(v);
                if ((k >> 24) == b0) {
                    uint32_t p = atomicAdd(&sh->ccount, 1u);
                    sh->cmp[p] = k;
                }
            }
        }
        __syncthreads();
    }

    for (int pass = 1; pass < 4; ++pass) {
        const int shift = 24 - 8 * pass;
        for (int i = tid; i < 1024; i += 256) sh->hist[i] = 0;
        __syncthreads();
        if (usec) {
            for (int i = tid; i < (int)cnt; i += 256) {
                uint32_t k = sh->cmp[i];
                if ((k & pmask) == prefix)
                    atomicAdd(&myhist[(k >> shift) & 0xFFu], 1u);
            }
        } else {
            for (int i = tid; i < MEDK / 4; i += 256) {
                float4 v4 = ((const float4*)ls)[i];
                float vv[4] = {v4.x, v4.y, v4.z, v4.w};
                #pragma unroll
                for (int e = 0; e < 4; ++e) {
                    float v = vv[e];
                    if (useabs) v = fabsf(v - sub);
                    uint32_t k = f2key(v);
                    if ((k & pmask) == prefix)
                        atomicAdd(&myhist[(k >> shift) & 0xFFu], 1u);
                }
            }
        }
        __syncthreads();
        bin_select(sh, rank);
        prefix |= sh->s_bin << shift;
        pmask  |= 0xFFu << shift;
        rank    = sh->s_rank;
        __syncthreads();
    }
    return key2f(prefix);
}

__global__ __launch_bounds__(256) void mad_kernel(const float* __restrict__ x,
                                                  float* __restrict__ mad)
{
    __shared__ float     ls[MEDK];       // 24000 B
    __shared__ SelShared sh;             // ~13.4 KB
    const int tr = blockIdx.x / NW;
    const int w  = blockIdx.x % NW;
    const float* xt = x + (size_t)tr * NT;
    const int t0 = w * MSTRIDE;
    if (t0 + MEDK <= NT) {
        // interior window: t0*4 bytes is 16B-aligned (3000*4 % 16 == 0)
        const float4* src4 = (const float4*)(xt + t0);
        float4* dst4 = (float4*)ls;
        for (int i = threadIdx.x; i < MEDK / 4; i += 256) dst4[i] = src4[i];
    } else {
        for (int i = threadIdx.x; i < MEDK; i += 256) {
            int g = t0 + i;
            int src = (g < NT) ? g : (2 * NT - 2 - g);   // numpy 'reflect'
            ls[i] = xt[src];
        }
    }
    __syncthreads();
    float med  = select_rank3000(ls, 0.0f, false, &sh);
    __syncthreads();
    float madv = select_rank3000(ls, med,  true,  &sh);
    if (threadIdx.x == 0) mad[tr * NW + w] = madv;
}

__global__ __launch_bounds__(256) void detect_kernel(const float* __restrict__ x,
                                                     const float* __restrict__ mad,
                                                     uint32_t* __restrict__ counters,
                                                     uint64_t* __restrict__ det)
{
    __shared__ float smad[NW];
    const int tr = blockIdx.x / DCHUNKS;
    const int ch = blockIdx.x % DCHUNKS;
    const float* xt = x + (size_t)tr * NT;
    for (int i = threadIdx.x; i < NW; i += 256) smad[i] = mad[tr * NW + i];
    __syncthreads();
    const int tbeg = ch * (NT / DCHUNKS);
    const int tend = tbeg + (NT / DCHUNKS);
    for (int t = tbeg + threadIdx.x * 4; t < tend; t += 256 * 4) {
        float4 v4 = *(const float4*)(xt + t);    // tbeg,t multiples of 4 -> aligned
        float vv[4] = {v4.x, v4.y, v4.z, v4.w};
        #pragma unroll
        for (int k = 0; k < 4; ++k) {
            int   tt = t + k;
            float v  = vv[k];
            // bilinear interp of mad along time (align_corners=False, clamped)
            float pos = ((float)tt + 0.5f) / (float)MSTRIDE - 0.5f;
            pos = fmaxf(pos, 0.0f);
            int   x0 = min((int)floorf(pos), NW - 1);
            int   x1 = min(x0 + 1, NW - 1);
            float wg = pos - (float)x0;
            float m  = smad[x0] * (1.0f - wg) + smad[x1] * wg;
            if (v > RATIO_F * m) {                       // almost never true
                bool ismax = true;
                int lo = max(tt - HALFW, 0), hi = min(tt + HALFW, NT - 1);
                for (int j = lo; j <= hi && ismax; ++j) ismax = (xt[j] <= v);
                if (ismax) {
                    uint32_t slot = atomicAdd(&counters[tr], 1u);
                    if (slot < DETCAP)
                        det[(size_t)tr * DETCAP + slot] =
                            ((uint64_t)f2key(v) << 32) | (uint32_t)(~(uint32_t)tt);
                }
            }
        }
    }
}

__global__ __launch_bounds__(64) void finalize_kernel(const float* __restrict__ x,
                                                      const uint32_t* __restrict__ counters,
                                                      const uint64_t* __restrict__ det,
                                                      float* __restrict__ out)
{
    __shared__ uint64_t sdet[DETCAP];
    __shared__ int sposs[TOPK];
    __shared__ int snegs[TOPK];
    __shared__ int s_np, s_nn;
    const int tr   = blockIdx.x;
    const int lane = threadIdx.x;
    const int D = (int)min(counters[tr], (uint32_t)DETCAP);
    for (int i = lane; i < D; i += 64) sdet[i] = det[(size_t)tr * DETCAP + i];
    if (lane == 0) { s_np = 0; s_nn = 0; }
    __syncthreads();

    const float* xt = x + (size_t)tr * NT;
    // first TOPK non-negative-sign (excluding detections) and first TOPK
    // negative-sign indices, ascending index order (XLA top_k tie semantics:
    // masked = x*0 keeps the sign; +0.0 sorts above -0.0, ties by index)
    for (int base = 0; base < NT; base += 64) {
        int np0 = s_np, nn0 = s_nn;
        if (np0 >= TOPK && nn0 >= TOPK) break;
        int  t     = base + lane;
        bool valid = (t < NT);
        uint32_t bits = valid ? __float_as_uint(xt[t]) : 0u;
        bool nonneg = valid && !(bits >> 31);
        bool neg    = valid &&  (bits >> 31);
        if (nonneg && D > 0) {
            for (int i = 0; i < D; ++i) {
                int dt = (int)(~(uint32_t)(sdet[i] & 0xFFFFFFFFull));
                if (dt == t) { nonneg = false; break; }
            }
        }
        unsigned long long bp = __ballot(nonneg);
        unsigned long long bn = __ballot(neg);
        unsigned long long below = (1ull << lane) - 1ull;
        int pidx = np0 + __popcll(bp & below);
        int nidx = nn0 + __popcll(bn & below);
        if (nonneg && pidx < TOPK) sposs[pidx] = t;
        if (neg    && nidx < TOPK) snegs[nidx] = t;
        __syncthreads();
        if (lane == 0) { s_np = np0 + __popcll(bp); s_nn = nn0 + __popcll(bn); }
        __syncthreads();
    }
    __syncthreads();

    if (lane == 0) {  // sort detections descending by total-order key (D tiny)
        for (int i = 1; i < D; ++i) {
            uint64_t k = sdet[i]; int j = i - 1;
            while (j >= 0 && sdet[j] < k) { sdet[j + 1] = sdet[j]; --j; }
            sdet[j + 1] = k;
        }
    }
    __syncthreads();

    const int nd   = min(D, TOPK);
    const int npos = min(s_np, TOPK);
    float* oscore = out + (size_t)tr * TOPK;
    float* oidx   = out + (size_t)NTRACE * TOPK + (size_t)tr * TOPK;
    for (int j = lane; j < TOPK; j += 64) {
        float sc; int idx;
        if (j < nd) {
            uint64_t k = sdet[j];
            sc  = key2f((uint32_t)(k >> 32));
            idx = (int)(~(uint32_t)(k & 0xFFFFFFFFull));
        } else if (j - nd < npos) {
            sc = 0.0f;  idx = sposs[j - nd];
        } else {
            int jj = j - nd - npos;
            sc = -0.0f; idx = (jj < TOPK) ? snegs[jj] : 0;
        }
        oscore[j] = sc;
        oidx[j]   = (float)idx;   // tuple output buffer is read back as f32
    }
}

extern "C" void kernel_launch(void* const* d_in, const int* in_sizes, int n_in,
                              void* d_out, int out_size, void* d_ws, size_t ws_size,
                              hipStream_t stream)
{
    const float* x = (const float*)d_in[0];
    float* out = (float*)d_out;
    char* ws = (char*)d_ws;
    float*    mad      = (float*)ws;                       // 96*121*4 = 46464 B
    uint32_t* counters = (uint32_t*)(ws + 46464);          // 384 B
    uint64_t* det      = (uint64_t*)(ws + 46464 + 384);    // 96*128*8 B (8-aligned)

    hipMemsetAsync(counters, 0, NTRACE * sizeof(uint32_t), stream);
    hipLaunchKernelGGL(mad_kernel,    dim3(NTRACE * NW),      dim3(256), 0, stream, x, mad);
    hipLaunchKernelGGL(detect_kernel, dim3(NTRACE * DCHUNKS), dim3(256), 0, stream, x, mad, counters, det);
    hipLaunchKernelGGL(finalize_kernel, dim3(NTRACE),         dim3(64),  0, stream, x, counters, det, out);
}

// Round 5
// 493.219 us; speedup vs baseline: 2.7907x; 1.1159x over previous
//
#include <hip/hip_runtime.h>
#include <stdint.h>

#define NT      360000
#define NTRACE  96
#define MEDK    6000
#define MSTRIDE 3000
#define NW      121      // number of MAD windows per trace
#define HALFW   50       // maxpool half-window (101 total)
#define TOPK    100
#define DETCAP  128      // max detections stored per trace (expected: 0)
#define RATIO_F 10.0f
#define DCHUNKS 24       // detect kernel: chunks per trace (15000 samples each)
#define CAP     2304     // compaction buffer (MAD bin ~1800+5sigma < 2304)
#define NCOPY   8        // histogram copies (per half-wave)
#define HSTRIDE 257      // copy stride in words: offsets copies into distinct banks
#define NSLOT   6        // float4 slots per thread (6*256*4 >= 6000)

// ---- float <-> sortable key (total order, -0.0 < +0.0, matches XLA top_k) ----
__device__ __forceinline__ uint32_t f2key(float f) {
    uint32_t u = __float_as_uint(f);
    return u ^ (uint32_t)(((int32_t)u >> 31) | 0x80000000);   // branchless
}
__device__ __forceinline__ float key2f(uint32_t k) {
    uint32_t u = (k & 0x80000000u) ? (k & 0x7fffffffu) : ~k;
    return __uint_as_float(u);
}

struct SelShared {
    uint32_t hist[NCOPY * HSTRIDE];   // 8 copies, bank-offset by stride 257
    uint32_t cmp[CAP];                // compacted keys of the pass-0 winning bin
    uint32_t segtot[4];
    uint32_t s_bin, s_rank, s_cnt, ccount;
};

// Find bin containing `rank` from NCOPY-copy 256-bin histogram.
__device__ void bin_select(SelShared* sh, uint32_t rank)
{
    const int tid  = threadIdx.x;
    const int lane = tid & 63;
    const int wv   = tid >> 6;
    uint32_t c = 0;
    #pragma unroll
    for (int j = 0; j < NCOPY; ++j) c += sh->hist[j * HSTRIDE + tid];
    uint32_t incl = c;
    #pragma unroll
    for (int off = 1; off < 64; off <<= 1) {
        uint32_t v = __shfl_up(incl, off);
        if (lane >= off) incl += v;
    }
    if (lane == 63) sh->segtot[wv] = incl;
    __syncthreads();
    uint32_t segoff = 0;
    for (int j = 0; j < wv; ++j) segoff += sh->segtot[j];
    incl += segoff;
    uint32_t excl = incl - c;
    if (rank > excl && rank <= incl) {   // exactly one thread true
        sh->s_bin = (uint32_t)tid; sh->s_rank = rank - excl; sh->s_cnt = c;
    }
    __syncthreads();
}

__device__ __forceinline__ void zero_hist(SelShared* sh)
{
    uint4* h4 = (uint4*)sh->hist;                 // NCOPY*HSTRIDE = 2056 = 514*4
    for (int i = threadIdx.x; i < 514; i += 256) h4[i] = make_uint4(0, 0, 0, 0);
}

// Exact 3000th-smallest (1-indexed == lower median of 6000) over the 24 values
// each thread holds in registers. Pass 0: 8-bit MSB histogram from regs; then
// compact the winning bin to LDS (wave-aggregated atomic) and run passes 1-3
// over the compacted keys. Fallback: full reg-scan filtered passes (exactness
// for arbitrary input).
__device__ float select_from_regs(const float4 (&r)[NSLOT], float sub, bool useabs,
                                  SelShared* sh)
{
    const int tid  = threadIdx.x;
    const int lane = tid & 63;
    uint32_t* myhist = &sh->hist[(tid >> 5) * HSTRIDE];

    zero_hist(sh);
    if (tid == 0) sh->ccount = 0;
    __syncthreads();
    #pragma unroll
    for (int k = 0; k < NSLOT; ++k) {
        if (k * 256 + tid < MEDK / 4) {
            float vv[4] = {r[k].x, r[k].y, r[k].z, r[k].w};
            #pragma unroll
            for (int e = 0; e < 4; ++e) {
                float v = vv[e];
                if (useabs) v = fabsf(v - sub);
                atomicAdd(&myhist[f2key(v) >> 24], 1u);
            }
        }
    }
    __syncthreads();
    bin_select(sh, 3000u);
    const uint32_t b0 = sh->s_bin, cnt = sh->s_cnt;
    uint32_t rank   = sh->s_rank;
    uint32_t prefix = b0 << 24;
    uint32_t pmask  = 0xFF000000u;
    const bool usec = (cnt <= CAP);

    if (usec) {   // compact winning-bin keys into cmp[] (wave-aggregated)
        #pragma unroll
        for (int k = 0; k < NSLOT; ++k) {
            bool valid = (k * 256 + tid < MEDK / 4);
            float vv[4] = {r[k].x, r[k].y, r[k].z, r[k].w};
            #pragma unroll
            for (int e = 0; e < 4; ++e) {
                uint32_t key = 0; bool m = false;
                if (valid) {
                    float v = vv[e];
                    if (useabs) v = fabsf(v - sub);
                    key = f2key(v);
                    m = ((key >> 24) == b0);
                }
                unsigned long long b = __ballot(m);
                if (b) {
                    int leader = __ffsll((unsigned long long)b) - 1;
                    uint32_t pcnt = (uint32_t)__popcll(b & ((1ull << lane) - 1ull));
                    uint32_t wbase = 0;
                    if (lane == leader) wbase = atomicAdd(&sh->ccount, (uint32_t)__popcll(b));
                    wbase = __shfl(wbase, leader);
                    if (m) sh->cmp[wbase + pcnt] = key;
                }
            }
        }
        __syncthreads();
    }

    for (int pass = 1; pass < 4; ++pass) {
        const int shift = 24 - 8 * pass;
        zero_hist(sh);
        __syncthreads();
        if (usec) {
            for (int i = tid; i < (int)cnt; i += 256) {
                uint32_t k = sh->cmp[i];
                if ((k & pmask) == prefix)
                    atomicAdd(&myhist[(k >> shift) & 0xFFu], 1u);
            }
        } else {
            #pragma unroll
            for (int k = 0; k < NSLOT; ++k) {
                if (k * 256 + tid < MEDK / 4) {
                    float vv[4] = {r[k].x, r[k].y, r[k].z, r[k].w};
                    #pragma unroll
                    for (int e = 0; e < 4; ++e) {
                        float v = vv[e];
                        if (useabs) v = fabsf(v - sub);
                        uint32_t kk = f2key(v);
                        if ((kk & pmask) == prefix)
                            atomicAdd(&myhist[(kk >> shift) & 0xFFu], 1u);
                    }
                }
            }
        }
        __syncthreads();
        bin_select(sh, rank);
        prefix |= sh->s_bin << shift;
        pmask  |= 0xFFu << shift;
        rank    = sh->s_rank;
        __syncthreads();
    }
    return key2f(prefix);
}

__global__ __launch_bounds__(256, 5) void mad_kernel(const float* __restrict__ x,
                                                     float* __restrict__ mad)
{
    __shared__ SelShared sh;             // ~17.5 KB
    const int tr = blockIdx.x / NW;
    const int w  = blockIdx.x % NW;
    const float* xt = x + (size_t)tr * NT;
    const int t0 = w * MSTRIDE;

    float4 r[NSLOT];                     // 24 window values per thread, in regs
    if (t0 + MEDK <= NT) {
        const float4* src4 = (const float4*)(xt + t0);   // t0*4 is 16B-aligned
        #pragma unroll
        for (int k = 0; k < NSLOT; ++k) {
            int i4 = k * 256 + threadIdx.x;
            r[k] = (i4 < MEDK / 4) ? src4[i4] : make_float4(0.f, 0.f, 0.f, 0.f);
        }
    } else {
        #pragma unroll
        for (int k = 0; k < NSLOT; ++k) {
            int i4 = k * 256 + threadIdx.x;
            float tmp[4] = {0.f, 0.f, 0.f, 0.f};
            if (i4 < MEDK / 4) {
                #pragma unroll
                for (int e = 0; e < 4; ++e) {
                    int g = t0 + i4 * 4 + e;
                    int src = (g < NT) ? g : (2 * NT - 2 - g);   // numpy 'reflect'
                    tmp[e] = xt[src];
                }
            }
            r[k] = make_float4(tmp[0], tmp[1], tmp[2], tmp[3]);
        }
    }
    __syncthreads();
    float med  = select_from_regs(r, 0.0f, false, &sh);
    __syncthreads();
    float madv = select_from_regs(r, med,  true,  &sh);
    if (threadIdx.x == 0) mad[tr * NW + w] = madv;
}

__global__ __launch_bounds__(256) void detect_kernel(const float* __restrict__ x,
                                                     const float* __restrict__ mad,
                                                     uint32_t* __restrict__ counters,
                                                     uint64_t* __restrict__ det)
{
    __shared__ float smad[NW];
    const int tr = blockIdx.x / DCHUNKS;
    const int ch = blockIdx.x % DCHUNKS;
    const float* xt = x + (size_t)tr * NT;
    for (int i = threadIdx.x; i < NW; i += 256) smad[i] = mad[tr * NW + i];
    __syncthreads();
    const int tbeg = ch * (NT / DCHUNKS);
    const int tend = tbeg + (NT / DCHUNKS);
    const int stride = 256 * 4;
    int t0 = tbeg + threadIdx.x * 4;
    float4 nxt = (t0 < tend) ? *(const float4*)(xt + t0)
                             : make_float4(0.f, 0.f, 0.f, 0.f);
    for (int t = t0; t < tend; t += stride) {
        float4 v4 = nxt;
        int tn = t + stride;
        if (tn < tend) nxt = *(const float4*)(xt + tn);   // prefetch next iter
        float vv[4] = {v4.x, v4.y, v4.z, v4.w};
        #pragma unroll
        for (int k = 0; k < 4; ++k) {
            int   tt = t + k;
            float v  = vv[k];
            // bilinear interp of mad along time (align_corners=False, clamped)
            float pos = ((float)tt + 0.5f) / (float)MSTRIDE - 0.5f;
            pos = fmaxf(pos, 0.0f);
            int   x0 = min((int)floorf(pos), NW - 1);
            int   x1 = min(x0 + 1, NW - 1);
            float wg = pos - (float)x0;
            float m  = smad[x0] * (1.0f - wg) + smad[x1] * wg;
            if (v > RATIO_F * m) {                       // almost never true
                bool ismax = true;
                int lo = max(tt - HALFW, 0), hi = min(tt + HALFW, NT - 1);
                for (int j = lo; j <= hi && ismax; ++j) ismax = (xt[j] <= v);
                if (ismax) {
                    uint32_t slot = atomicAdd(&counters[tr], 1u);
                    if (slot < DETCAP)
                        det[(size_t)tr * DETCAP + slot] =
                            ((uint64_t)f2key(v) << 32) | (uint32_t)(~(uint32_t)tt);
                }
            }
        }
    }
}

__global__ __launch_bounds__(64) void finalize_kernel(const float* __restrict__ x,
                                                      const uint32_t* __restrict__ counters,
                                                      const uint64_t* __restrict__ det,
                                                      float* __restrict__ out)
{
    __shared__ uint64_t sdet[DETCAP];
    __shared__ int sposs[TOPK];
    __shared__ int snegs[TOPK];
    __shared__ int s_np, s_nn;
    const int tr   = blockIdx.x;
    const int lane = threadIdx.x;
    const int D = (int)min(counters[tr], (uint32_t)DETCAP);
    for (int i = lane; i < D; i += 64) sdet[i] = det[(size_t)tr * DETCAP + i];
    if (lane == 0) { s_np = 0; s_nn = 0; }
    __syncthreads();

    const float* xt = x + (size_t)tr * NT;
    // first TOPK non-negative-sign (excluding detections) and first TOPK
    // negative-sign indices, ascending index order (XLA top_k tie semantics:
    // masked = x*0 keeps the sign; +0.0 sorts above -0.0, ties by index)
    for (int base = 0; base < NT; base += 64) {
        int np0 = s_np, nn0 = s_nn;
        if (np0 >= TOPK && nn0 >= TOPK) break;
        int  t     = base + lane;
        bool valid = (t < NT);
        uint32_t bits = valid ? __float_as_uint(xt[t]) : 0u;
        bool nonneg = valid && !(bits >> 31);
        bool neg    = valid &&  (bits >> 31);
        if (nonneg && D > 0) {
            for (int i = 0; i < D; ++i) {
                int dt = (int)(~(uint32_t)(sdet[i] & 0xFFFFFFFFull));
                if (dt == t) { nonneg = false; break; }
            }
        }
        unsigned long long bp = __ballot(nonneg);
        unsigned long long bn = __ballot(neg);
        unsigned long long below = (1ull << lane) - 1ull;
        int pidx = np0 + __popcll(bp & below);
        int nidx = nn0 + __popcll(bn & below);
        if (nonneg && pidx < TOPK) sposs[pidx] = t;
        if (neg    && nidx < TOPK) snegs[nidx] = t;
        __syncthreads();
        if (lane == 0) { s_np = np0 + __popcll(bp); s_nn = nn0 + __popcll(bn); }
        __syncthreads();
    }
    __syncthreads();

    if (lane == 0) {  // sort detections descending by total-order key (D tiny)
        for (int i = 1; i < D; ++i) {
            uint64_t k = sdet[i]; int j = i - 1;
            while (j >= 0 && sdet[j] < k) { sdet[j + 1] = sdet[j]; --j; }
            sdet[j + 1] = k;
        }
    }
    __syncthreads();

    const int nd   = min(D, TOPK);
    const int npos = min(s_np, TOPK);
    float* oscore = out + (size_t)tr * TOPK;
    float* oidx   = out + (size_t)NTRACE * TOPK + (size_t)tr * TOPK;
    for (int j = lane; j < TOPK; j += 64) {
        float sc; int idx;
        if (j < nd) {
            uint64_t k = sdet[j];
            sc  = key2f((uint32_t)(k >> 32));
            idx = (int)(~(uint32_t)(k & 0xFFFFFFFFull));
        } else if (j - nd < npos) {
            sc = 0.0f;  idx = sposs[j - nd];
        } else {
            int jj = j - nd - npos;
            sc = -0.0f; idx = (jj < TOPK) ? snegs[jj] : 0;
        }
        oscore[j] = sc;
        oidx[j]   = (float)idx;   // tuple output buffer is read back as f32
    }
}

extern "C" void kernel_launch(void* const* d_in, const int* in_sizes, int n_in,
                              void* d_out, int out_size, void* d_ws, size_t ws_size,
                              hipStream_t stream)
{
    const float* x = (const float*)d_in[0];
    float* out = (float*)d_out;
    char* ws = (char*)d_ws;
    float*    mad      = (float*)ws;                       // 96*121*4 = 46464 B
    uint32_t* counters = (uint32_t*)(ws + 46464);          // 384 B
    uint64_t* det      = (uint64_t*)(ws + 46464 + 384);    // 96*128*8 B (8-aligned)

    hipMemsetAsync(counters, 0, NTRACE * sizeof(uint32_t), stream);
    hipLaunchKernelGGL(mad_kernel,    dim3(NTRACE * NW),      dim3(256), 0, stream, x, mad);
    hipLaunchKernelGGL(detect_kernel, dim3(NTRACE * DCHUNKS), dim3(256), 0, stream, x, mad, counters, det);
    hipLaunchKernelGGL(finalize_kernel, dim3(NTRACE),         dim3(64),  0, stream, x, counters, det, out);
}